// Round 3
// baseline (143.494 us; speedup 1.0000x reference)
//
#include <hip/hip_runtime.h>

// h_t = (1 - f_t) * z_t + f_t * h_{t-1},  h_{-1} = 0, scan along S (last axis).
// (B,H,S) = (32,1024,2048) fp32. One 256-thread block per row.
// Each thread owns TWO 4-element chunks: A = [4*tid, 4*tid+4) in the first
// half of the row, B = [1024 + 4*tid, ...) in the second half. Every float4
// load/store is perfectly lane-contiguous (64 lanes x 16 B = 1 KiB/instr).
// Two block scans (A-half then B-half), stitched by the A-half total.

#define SEQ_LEN 2048
#define THREADS 256
#define CHUNK   4

typedef float fvec4 __attribute__((ext_vector_type(4)));  // native clang vector

// Block-wide inclusive scan of per-thread transforms (p,l) where T(h)=p*h+l,
// thread order = chunk order. Returns the EXCLUSIVE prefix transform for this
// thread (ep,el) and the block-total transform (tp,tl).
__device__ __forceinline__ void scan_block(
    float p, float l, int lane, int wave,
    float* wp, float* wl,
    float& ep, float& el, float& tp, float& tl)
{
    float cp = p, cl = l;
#pragma unroll
    for (int d = 1; d < 64; d <<= 1) {
        float pp = __shfl_up(cp, d);
        float pl = __shfl_up(cl, d);
        if (lane >= d) {
            cl = fmaf(cp, pl, cl);   // later(current) ∘ earlier(pp,pl)
            cp = cp * pp;
        }
    }
    if (lane == 63) { wp[wave] = cp; wl[wave] = cl; }
    __syncthreads();

    // exclusive within wave
    ep = __shfl_up(cp, 1);
    el = __shfl_up(cl, 1);
    if (lane == 0) { ep = 1.0f; el = 0.0f; }

    // transforms of waves before this one, and block total
    float bp = 1.0f, bl = 0.0f;
    float qp = 1.0f, ql = 0.0f;
#pragma unroll
    for (int w = 0; w < THREADS / 64; ++w) {
        float wpw = wp[w], wlw = wl[w];
        if (w < wave) { bl = fmaf(wpw, bl, wlw); bp *= wpw; }
        ql = fmaf(wpw, ql, wlw); qp *= wpw;
    }
    // exclusive block prefix for this thread = (ep,el) ∘ (bp,bl)
    el = fmaf(ep, bl, el);
    ep = ep * bp;
    tp = qp; tl = ql;
}

__global__ __launch_bounds__(THREADS) void fpool_scan_kernel(
    const float* __restrict__ f,
    const float* __restrict__ z,
    float* __restrict__ out)
{
    const long long row  = blockIdx.x;
    const long long base = row * (long long)SEQ_LEN;
    const int tid  = threadIdx.x;
    const int lane = tid & 63;
    const int wave = tid >> 6;

    const float4* f4 = reinterpret_cast<const float4*>(f + base);
    const float4* z4 = reinterpret_cast<const float4*>(z + base);
    fvec4* o4 = reinterpret_cast<fvec4*>(out + base);

    // ---- perfectly coalesced loads: lane-contiguous float4 ----
    float4 fA = f4[tid];            // first half of row
    float4 zA = z4[tid];
    float4 fB = f4[THREADS + tid];  // second half of row
    float4 zB = z4[THREADS + tid];

    // ---- local prefix transforms within each 4-chunk ----
    float aA[CHUNK] = {fA.x, fA.y, fA.z, fA.w};
    float vA[CHUNK] = {zA.x, zA.y, zA.z, zA.w};
    float aB[CHUNK] = {fB.x, fB.y, fB.z, fB.w};
    float vB[CHUNK] = {zB.x, zB.y, zB.z, zB.w};

    float PA[CHUNK], LA[CHUNK], PB[CHUNK], LB[CHUNK];
    {
        float p = 1.0f, l = 0.0f;
#pragma unroll
        for (int i = 0; i < CHUNK; ++i) {
            l = fmaf(aA[i], l, (1.0f - aA[i]) * vA[i]);
            p = p * aA[i];
            PA[i] = p; LA[i] = l;
        }
    }
    {
        float p = 1.0f, l = 0.0f;
#pragma unroll
        for (int i = 0; i < CHUNK; ++i) {
            l = fmaf(aB[i], l, (1.0f - aB[i]) * vB[i]);
            p = p * aB[i];
            PB[i] = p; LB[i] = l;
        }
    }

    __shared__ float wpA[THREADS / 64], wlA[THREADS / 64];
    __shared__ float wpB[THREADS / 64], wlB[THREADS / 64];

    // ---- scan first half ----
    float epA, elA, tpA, tlA;
    scan_block(PA[CHUNK - 1], LA[CHUNK - 1], lane, wave, wpA, wlA,
               epA, elA, tpA, tlA);
    const float hA = elA;  // exclusive prefix applied to h0 = 0

    // ---- scan second half ----
    float epB, elB, tpB, tlB;
    scan_block(PB[CHUNK - 1], LB[CHUNK - 1], lane, wave, wpB, wlB,
               epB, elB, tpB, tlB);
    const float h_half = tlA;                 // state after first half (h0=0)
    const float hB = fmaf(epB, h_half, elB);  // state before this B chunk

    // ---- finalize + nontemporal contiguous stores ----
    fvec4 oA, oB;
    oA.x = fmaf(PA[0], hA, LA[0]);
    oA.y = fmaf(PA[1], hA, LA[1]);
    oA.z = fmaf(PA[2], hA, LA[2]);
    oA.w = fmaf(PA[3], hA, LA[3]);
    oB.x = fmaf(PB[0], hB, LB[0]);
    oB.y = fmaf(PB[1], hB, LB[1]);
    oB.z = fmaf(PB[2], hB, LB[2]);
    oB.w = fmaf(PB[3], hB, LB[3]);

    __builtin_nontemporal_store(oA, &o4[tid]);
    __builtin_nontemporal_store(oB, &o4[THREADS + tid]);
}

extern "C" void kernel_launch(void* const* d_in, const int* in_sizes, int n_in,
                              void* d_out, int out_size, void* d_ws, size_t ws_size,
                              hipStream_t stream) {
    const float* f = reinterpret_cast<const float*>(d_in[0]);
    const float* z = reinterpret_cast<const float*>(d_in[1]);
    float* out = reinterpret_cast<float*>(d_out);

    const long long total = in_sizes[0];      // B*H*S
    const int rows = (int)(total / SEQ_LEN);  // B*H = 32768

    fpool_scan_kernel<<<rows, THREADS, 0, stream>>>(f, z, out);
}